// Round 1
// baseline (123.977 us; speedup 1.0000x reference)
//
#include <hip/hip_runtime.h>
#include <math.h>

// Problem constants
#define NGRID   11
#define NPNT    121     // NGRID*NGRID
#define NFACE   6
#define NHAND   21
#define NPAIR   126     // NHAND*NFACE
#define NCONT   10
#define NBUCKET 256

__device__ __constant__ int c_face[6][4] = {
    {0,1,2,3},{0,4,2,6},{0,1,4,5},{1,3,5,7},{2,3,6,7},{4,5,6,7}};

__global__ void zero_ws_kernel(float* ws) {
    int t = threadIdx.x;
    if (t < NBUCKET * 2) ws[t] = 0.0f;
}

__launch_bounds__(128)
__global__ void affinity_kernel(const float* __restrict__ poses,
                                float* __restrict__ ws) {
    const int b = blockIdx.x;
    const int t = threadIdx.x;

    __shared__ float sh_pose[87];             // 21*3 hand + 8*3 obj
    __shared__ float sh_opts[NFACE * NPNT * 3];
    __shared__ float sh_d2[NPAIR];
    __shared__ int   sh_pm[NPAIR];
    __shared__ int   sh_ch[NCONT];
    __shared__ float sh_ctr[NCONT][4];

    const float* src = poses + (size_t)b * 87;
    if (t < 87) sh_pose[t] = src[t];
    __syncthreads();

    const float* hand = sh_pose;       // 21 x 3
    const float* obj  = sh_pose + 63;  // 8 x 3

    // ---- face points: obj_pts[f][p][c] = sum_k grid[p][k] * obj[FACE[f][k]][c]
    // grid weights computed in f64 then cast to f32 to match numpy/linspace.
    for (int pp = t; pp < NFACE * NPNT; pp += 128) {
        const int f  = pp / NPNT;
        const int p  = pp - f * NPNT;
        const int iu = p / NGRID;
        const int iv = p - iu * NGRID;
        const double u = iu * 0.1;
        const double v = iv * 0.1;
        const float w0 = (float)(v * (1.0 - u));
        const float w1 = (float)(v * u);
        const float w2 = (float)((1.0 - v) * (1.0 - u));
        const float w3 = (float)(u * (1.0 - v));
        const int i0 = c_face[f][0] * 3, i1 = c_face[f][1] * 3,
                  i2 = c_face[f][2] * 3, i3 = c_face[f][3] * 3;
        #pragma unroll
        for (int c = 0; c < 3; ++c) {
            sh_opts[pp * 3 + c] = w0 * obj[i0 + c] + w1 * obj[i1 + c]
                                + w2 * obj[i2 + c] + w3 * obj[i3 + c];
        }
    }
    __syncthreads();

    // ---- per (hand i, face f): min + argmin over the 121 face points.
    // d2 uses the reference formula (xx+yy) - 2*zz  (+1e-6 deferred to sqrt).
    if (t < NPAIR) {
        const int i = t / 6;
        const int f = t - i * 6;
        const float hx = hand[i * 3 + 0], hy = hand[i * 3 + 1], hz = hand[i * 3 + 2];
        const float xx = hx * hx + hy * hy + hz * hz;
        const float* fp = &sh_opts[f * NPNT * 3];
        float best = 3.0e38f;
        int   bp   = 0;
        for (int p = 0; p < NPNT; ++p) {
            const float px = fp[p * 3 + 0], py = fp[p * 3 + 1], pz = fp[p * 3 + 2];
            const float yy = px * px + py * py + pz * pz;
            const float zz = hx * px + hy * py + hz * pz;
            const float d2 = (xx + yy) - 2.0f * zz;
            if (d2 < best) { best = d2; bp = p; }   // strict < => first-index argmin
        }
        sh_d2[t] = best;
        sh_pm[t] = bp;
    }
    __syncthreads();

    // ---- wave 0: select the 10 smallest of the 126 (stable on index).
    if (t < 64) {
        float v0 = (t      < NPAIR) ? sh_d2[t]      : 3.0e38f;
        float v1 = (t + 64 < NPAIR) ? sh_d2[t + 64] : 3.0e38f;
        for (int c = 0; c < NCONT; ++c) {
            float bv; int bi;
            if (v1 < v0) { bv = v1; bi = t + 64; } else { bv = v0; bi = t; }
            #pragma unroll
            for (int off = 32; off >= 1; off >>= 1) {
                const float ov = __shfl_xor(bv, off, 64);
                const int   oi = __shfl_xor(bi, off, 64);
                if (ov < bv || (ov == bv && oi < bi)) { bv = ov; bi = oi; }
            }
            if (t == 0) sh_ch[c] = bi;
            if (bi == t)      v0 = 3.0e38f;   // remove chosen element
            if (bi == t + 64) v1 = 3.0e38f;
        }
    }
    __syncthreads();

    // ---- per-contact normal vectors and mask (threads 0..9)
    if (t < NCONT) {
        const int ci = sh_ch[t];
        const int f  = ci - (ci / 6) * 6;
        const int p  = sh_pm[ci];
        const float dist = sqrtf(sh_d2[ci] + 1e-6f);
        const float* ct = &sh_opts[(f * NPNT + p) * 3];
        const float cx = ct[0], cy = ct[1], cz = ct[2];

        // points1 = mean(obj[0:4]), points2 = mean(obj[4:8])  (/4 == *0.25 exact)
        float p1x = (((obj[0]  + obj[3])  + obj[6])  + obj[9])  * 0.25f;
        float p1y = (((obj[1]  + obj[4])  + obj[7])  + obj[10]) * 0.25f;
        float p1z = (((obj[2]  + obj[5])  + obj[8])  + obj[11]) * 0.25f;
        float p2x = (((obj[12] + obj[15]) + obj[18]) + obj[21]) * 0.25f;
        float p2y = (((obj[13] + obj[16]) + obj[19]) + obj[22]) * 0.25f;
        float p2z = (((obj[14] + obj[17]) + obj[20]) + obj[23]) * 0.25f;

        float l1 = 0.0f, l2 = 0.0f;
        #pragma unroll
        for (int e = 0; e < 4; ++e) {
            const int a = e, bb = (e + 1) & 3;
            {
                const float dx = obj[a * 3 + 0] - obj[bb * 3 + 0];
                const float dy = obj[a * 3 + 1] - obj[bb * 3 + 1];
                const float dz = obj[a * 3 + 2] - obj[bb * 3 + 2];
                l1 += sqrtf(dx * dx + dy * dy + dz * dz);
            }
            {
                const float dx = obj[(a + 4) * 3 + 0] - obj[(bb + 4) * 3 + 0];
                const float dy = obj[(a + 4) * 3 + 1] - obj[(bb + 4) * 3 + 1];
                const float dz = obj[(a + 4) * 3 + 2] - obj[(bb + 4) * 3 + 2];
                l2 += sqrtf(dx * dx + dy * dy + dz * dz);
            }
        }
        l1 *= 0.25f; l2 *= 0.25f;
        const float length = (l1 + l2) * 0.5f;
        const float m = (dist < length * 0.2f) ? 1.0f : 0.0f;

        const float dvx = p2x - p1x, dvy = p2y - p1y, dvz = p2z - p1z;
        const float dvn = sqrtf(dvx * dvx + dvy * dvy + dvz * dvz);
        const float den = dvn + 1e-5f;
        const float ndx = dvx / den, ndy = dvy / den, ndz = dvz / den;
        const float vcx = cx - p1x, vcy = cy - p1y, vcz = cz - p1z;
        const float inner = dvx * vcx + dvy * vcy + dvz * vcz;
        const float tp = inner / den;
        const float rx = p1x + ndx * tp, ry = p1y + ndy * tp, rz = p1z + ndz * tp;
        float nvx = cx - rx, nvy = cy - ry, nvz = cz - rz;
        const float nvn = sqrtf(nvx * nvx + nvy * nvy + nvz * nvz) + 1e-5f;
        nvx /= nvn; nvy /= nvn; nvz /= nvn;

        sh_ctr[t][0] = m * nvx;
        sh_ctr[t][1] = m * nvy;
        sh_ctr[t][2] = m * nvz;
        sh_ctr[t][3] = m;
    }
    __syncthreads();

    // ---- per-batch reduction:
    // sum(cos_sim*mask) == |sum_c m_c*nv_c|^2 ; mask.sum() == (sum_c m_c)^2
    if (t == 0) {
        float sx = 0.f, sy = 0.f, sz = 0.f, sk = 0.f;
        #pragma unroll
        for (int c = 0; c < NCONT; ++c) {
            sx += sh_ctr[c][0]; sy += sh_ctr[c][1];
            sz += sh_ctr[c][2]; sk += sh_ctr[c][3];
        }
        const float num = sx * sx + sy * sy + sz * sz;
        const float dnm = sk * sk;
        float* bucket = ws + 2 * (b & (NBUCKET - 1));
        atomicAdd(bucket + 0, num);
        atomicAdd(bucket + 1, dnm);
    }
}

__global__ void finalize_kernel(const float* __restrict__ ws,
                                float* __restrict__ out) {
    const int t = threadIdx.x;  // 64 threads
    double n = 0.0, d = 0.0;
    for (int k = t; k < NBUCKET; k += 64) {
        n += (double)ws[2 * k + 0];
        d += (double)ws[2 * k + 1];
    }
    #pragma unroll
    for (int off = 32; off >= 1; off >>= 1) {
        n += __shfl_xor(n, off, 64);
        d += __shfl_xor(d, off, 64);
    }
    if (t == 0) out[0] = (float)(n / (d + 1.0));
}

extern "C" void kernel_launch(void* const* d_in, const int* in_sizes, int n_in,
                              void* d_out, int out_size, void* d_ws, size_t ws_size,
                              hipStream_t stream) {
    const float* poses = (const float*)d_in[0];
    float* out = (float*)d_out;
    float* ws  = (float*)d_ws;
    const int bs = in_sizes[0] / 87;   // 29 keypoints * 3 coords

    hipLaunchKernelGGL(zero_ws_kernel, dim3(1), dim3(NBUCKET * 2), 0, stream, ws);
    hipLaunchKernelGGL(affinity_kernel, dim3(bs), dim3(128), 0, stream, poses, ws);
    hipLaunchKernelGGL(finalize_kernel, dim3(1), dim3(64), 0, stream, ws, out);
}

// Round 2
// 105.617 us; speedup vs baseline: 1.1738x; 1.1738x over previous
//
#include <hip/hip_runtime.h>
#include <math.h>

// Problem constants
#define NGRID   11
#define NPNT    121     // NGRID*NGRID
#define NFACE   6
#define NHAND   21
#define NPAIR   126     // NHAND*NFACE
#define NCONT   10
#define NBUCKET 256     // fallback atomic-bucket count

__device__ __constant__ int c_face[6][4] = {
    {0,1,2,3},{0,4,2,6},{0,1,4,5},{1,3,5,7},{2,3,6,7},{4,5,6,7}};

__global__ void zero_ws_kernel(float* ws, int n) {
    int t = blockIdx.x * 256 + threadIdx.x;
    if (t < n) ws[t] = 0.0f;
}

// mode: 1 = direct per-block store at slot b; 0 = atomicAdd into slot (b & slot_mask)
__launch_bounds__(128)
__global__ void affinity_kernel(const float* __restrict__ poses,
                                float* __restrict__ ws,
                                int mode, int slot_mask) {
    const int b = blockIdx.x;
    const int t = threadIdx.x;

    __shared__ float  sh_pose[87];                 // 21*3 hand + 8*3 obj
    __shared__ float4 sh_p4[NFACE * NPNT];         // (px,py,pz,-yy) per face point
    // scratch region: bilinear weights during staging, then d2/pm/ch/ctr
    __shared__ __align__(16) float sh_scr[4 * NPNT];  // 484 floats
    float4* sh_w4 = (float4*)sh_scr;               // [121] weights
    float*  sh_d2 = sh_scr;                        // [126]
    int*    sh_pm = (int*)(sh_scr + NPAIR);        // [126]
    int*    sh_ch = (int*)(sh_scr + 2 * NPAIR);    // [10]
    float*  sh_ctr = sh_scr + 2 * NPAIR + NCONT;   // [10][4]

    const float* src = poses + (size_t)b * 87;
    if (t < 87) sh_pose[t] = src[t];

    // ---- bilinear grid weights (f64 math to match np.linspace, cast f32)
    if (t < NPNT) {
        const int iu = t / NGRID;
        const int iv = t - iu * NGRID;
        const double u = iu * 0.1;
        const double v = iv * 0.1;
        float4 w;
        w.x = (float)(v * (1.0 - u));
        w.y = (float)(v * u);
        w.z = (float)((1.0 - v) * (1.0 - u));
        w.w = (float)(u * (1.0 - v));
        sh_w4[t] = w;
    }
    __syncthreads();

    const float* hand = sh_pose;       // 21 x 3
    const float* obj  = sh_pose + 63;  // 8 x 3

    // ---- stage face points as (px,py,pz,-yy)
    for (int pp = t; pp < NFACE * NPNT; pp += 128) {
        const int f = pp / NPNT;
        const int p = pp - f * NPNT;
        const float4 w = sh_w4[p];
        const int i0 = c_face[f][0] * 3, i1 = c_face[f][1] * 3,
                  i2 = c_face[f][2] * 3, i3 = c_face[f][3] * 3;
        const float px = w.x * obj[i0 + 0] + w.y * obj[i1 + 0]
                       + w.z * obj[i2 + 0] + w.w * obj[i3 + 0];
        const float py = w.x * obj[i0 + 1] + w.y * obj[i1 + 1]
                       + w.z * obj[i2 + 1] + w.w * obj[i3 + 1];
        const float pz = w.x * obj[i0 + 2] + w.y * obj[i1 + 2]
                       + w.z * obj[i2 + 2] + w.w * obj[i3 + 2];
        float4 o;
        o.x = px; o.y = py; o.z = pz;
        o.w = -(px * px + py * py + pz * pz);   // -yy
        sh_p4[pp] = o;
    }
    __syncthreads();

    // ---- per (hand i, face f): min + argmin over 121 points.
    // d2 = xx + yy - 2*h.p  ==  xx - q,  q = 2h.p - yy  (maximize q)
    if (t < NPAIR) {
        const int i = t / 6;
        const int f = t - i * 6;
        const float hx = hand[i * 3 + 0], hy = hand[i * 3 + 1], hz = hand[i * 3 + 2];
        const float xx  = hx * hx + hy * hy + hz * hz;
        const float hx2 = 2.0f * hx, hy2 = 2.0f * hy, hz2 = 2.0f * hz;
        const float4* fp = &sh_p4[f * NPNT];
        float qb = -3.0e38f;
        int   bp = 0;
        #pragma unroll 11
        for (int p = 0; p < NPNT; ++p) {
            const float4 v = fp[p];
            const float q = fmaf(hx2, v.x, fmaf(hy2, v.y, fmaf(hz2, v.z, v.w)));
            if (q > qb) { qb = q; bp = p; }   // strict > => first-index argmin of d2
        }
        sh_d2[t] = xx - qb;
        sh_pm[t] = bp;
    }
    __syncthreads();

    // ---- wave 0: select the 10 smallest of the 126 (stable on index).
    if (t < 64) {
        float v0 = (t      < NPAIR) ? sh_d2[t]      : 3.0e38f;
        float v1 = (t + 64 < NPAIR) ? sh_d2[t + 64] : 3.0e38f;
        for (int c = 0; c < NCONT; ++c) {
            float bv; int bi;
            if (v1 < v0) { bv = v1; bi = t + 64; } else { bv = v0; bi = t; }
            #pragma unroll
            for (int off = 32; off >= 1; off >>= 1) {
                const float ov = __shfl_xor(bv, off, 64);
                const int   oi = __shfl_xor(bi, off, 64);
                if (ov < bv || (ov == bv && oi < bi)) { bv = ov; bi = oi; }
            }
            if (t == 0) sh_ch[c] = bi;
            if (bi == t)      v0 = 3.0e38f;
            if (bi == t + 64) v1 = 3.0e38f;
        }
    }
    __syncthreads();

    // ---- per-contact normal vectors and mask (threads 0..9)
    if (t < NCONT) {
        const int ci = sh_ch[t];
        const int f  = ci - (ci / 6) * 6;
        const int p  = sh_pm[ci];
        const float dist = sqrtf(sh_d2[ci] + 1e-6f);
        const float4 ct = sh_p4[f * NPNT + p];
        const float cx = ct.x, cy = ct.y, cz = ct.z;

        float p1x = (((obj[0]  + obj[3])  + obj[6])  + obj[9])  * 0.25f;
        float p1y = (((obj[1]  + obj[4])  + obj[7])  + obj[10]) * 0.25f;
        float p1z = (((obj[2]  + obj[5])  + obj[8])  + obj[11]) * 0.25f;
        float p2x = (((obj[12] + obj[15]) + obj[18]) + obj[21]) * 0.25f;
        float p2y = (((obj[13] + obj[16]) + obj[19]) + obj[22]) * 0.25f;
        float p2z = (((obj[14] + obj[17]) + obj[20]) + obj[23]) * 0.25f;

        float l1 = 0.0f, l2 = 0.0f;
        #pragma unroll
        for (int e = 0; e < 4; ++e) {
            const int a = e, bb = (e + 1) & 3;
            {
                const float dx = obj[a * 3 + 0] - obj[bb * 3 + 0];
                const float dy = obj[a * 3 + 1] - obj[bb * 3 + 1];
                const float dz = obj[a * 3 + 2] - obj[bb * 3 + 2];
                l1 += sqrtf(dx * dx + dy * dy + dz * dz);
            }
            {
                const float dx = obj[(a + 4) * 3 + 0] - obj[(bb + 4) * 3 + 0];
                const float dy = obj[(a + 4) * 3 + 1] - obj[(bb + 4) * 3 + 1];
                const float dz = obj[(a + 4) * 3 + 2] - obj[(bb + 4) * 3 + 2];
                l2 += sqrtf(dx * dx + dy * dy + dz * dz);
            }
        }
        l1 *= 0.25f; l2 *= 0.25f;
        const float length = (l1 + l2) * 0.5f;
        const float m = (dist < length * 0.2f) ? 1.0f : 0.0f;

        const float dvx = p2x - p1x, dvy = p2y - p1y, dvz = p2z - p1z;
        const float dvn = sqrtf(dvx * dvx + dvy * dvy + dvz * dvz);
        const float den = dvn + 1e-5f;
        const float ndx = dvx / den, ndy = dvy / den, ndz = dvz / den;
        const float vcx = cx - p1x, vcy = cy - p1y, vcz = cz - p1z;
        const float inner = dvx * vcx + dvy * vcy + dvz * vcz;
        const float tp = inner / den;
        const float rx = p1x + ndx * tp, ry = p1y + ndy * tp, rz = p1z + ndz * tp;
        float nvx = cx - rx, nvy = cy - ry, nvz = cz - rz;
        const float nvn = sqrtf(nvx * nvx + nvy * nvy + nvz * nvz) + 1e-5f;
        nvx /= nvn; nvy /= nvn; nvz /= nvn;

        sh_ctr[t * 4 + 0] = m * nvx;
        sh_ctr[t * 4 + 1] = m * nvy;
        sh_ctr[t * 4 + 2] = m * nvz;
        sh_ctr[t * 4 + 3] = m;
    }
    __syncthreads();

    // sum(cos_sim*mask) == |sum_c m_c*nv_c|^2 ; mask.sum() == (sum_c m_c)^2
    if (t == 0) {
        float sx = 0.f, sy = 0.f, sz = 0.f, sk = 0.f;
        #pragma unroll
        for (int c = 0; c < NCONT; ++c) {
            sx += sh_ctr[c * 4 + 0]; sy += sh_ctr[c * 4 + 1];
            sz += sh_ctr[c * 4 + 2]; sk += sh_ctr[c * 4 + 3];
        }
        const float num = sx * sx + sy * sy + sz * sz;
        const float dnm = sk * sk;
        if (mode) {
            ws[2 * b + 0] = num;
            ws[2 * b + 1] = dnm;
        } else {
            float* bucket = ws + 2 * (b & slot_mask);
            atomicAdd(bucket + 0, num);
            atomicAdd(bucket + 1, dnm);
        }
    }
}

__launch_bounds__(1024)
__global__ void finalize_kernel(const float* __restrict__ ws,
                                float* __restrict__ out, int nslot) {
    const int t = threadIdx.x;  // 1024 threads = 16 waves
    __shared__ double sh_n[16], sh_d[16];
    double n = 0.0, d = 0.0;
    for (int k = t; k < nslot; k += 1024) {
        n += (double)ws[2 * k + 0];
        d += (double)ws[2 * k + 1];
    }
    #pragma unroll
    for (int off = 32; off >= 1; off >>= 1) {
        n += __shfl_xor(n, off, 64);
        d += __shfl_xor(d, off, 64);
    }
    const int w = t >> 6;
    if ((t & 63) == 0) { sh_n[w] = n; sh_d[w] = d; }
    __syncthreads();
    if (t == 0) {
        double nn = 0.0, dd = 0.0;
        #pragma unroll
        for (int i = 0; i < 16; ++i) { nn += sh_n[i]; dd += sh_d[i]; }
        out[0] = (float)(nn / (dd + 1.0));
    }
}

extern "C" void kernel_launch(void* const* d_in, const int* in_sizes, int n_in,
                              void* d_out, int out_size, void* d_ws, size_t ws_size,
                              hipStream_t stream) {
    const float* poses = (const float*)d_in[0];
    float* out = (float*)d_out;
    float* ws  = (float*)d_ws;
    const int bs = in_sizes[0] / 87;   // 29 keypoints * 3 coords

    const bool direct = (ws_size >= (size_t)bs * 2 * sizeof(float));
    if (direct) {
        hipLaunchKernelGGL(affinity_kernel, dim3(bs), dim3(128), 0, stream,
                           poses, ws, 1, 0);
        hipLaunchKernelGGL(finalize_kernel, dim3(1), dim3(1024), 0, stream,
                           ws, out, bs);
    } else {
        hipLaunchKernelGGL(zero_ws_kernel, dim3(1), dim3(256), 0, stream,
                           ws, NBUCKET * 2);
        hipLaunchKernelGGL(affinity_kernel, dim3(bs), dim3(128), 0, stream,
                           poses, ws, 0, NBUCKET - 1);
        hipLaunchKernelGGL(finalize_kernel, dim3(1), dim3(1024), 0, stream,
                           ws, out, NBUCKET);
    }
}